// Round 1
// baseline (21747.566 us; speedup 1.0000x reference)
//
#include <hip/hip_runtime.h>
#include <hip/hip_bf16.h>
#include <cstdint>

#define NN 50000
#define NE 800000

// ---------------- shared GEMM tile macros ----------------
// Thread mapping: 256 threads, cg = tid&15 -> output cols [8cg, 8cg+8),
// rg = tid>>4 -> output rows [4rg, 4rg+4). acc[4][8] in registers.

#define ACC_INIT(BPTR)                                                        \
  {                                                                           \
    const float4 bA_ = *(const float4*)((BPTR) + cg * 8);                     \
    const float4 bB_ = *(const float4*)((BPTR) + cg * 8 + 4);                 \
    _Pragma("unroll") for (int i_ = 0; i_ < 4; ++i_) {                        \
      acc[i_][0] = bA_.x; acc[i_][1] = bA_.y; acc[i_][2] = bA_.z;             \
      acc[i_][3] = bA_.w; acc[i_][4] = bB_.x; acc[i_][5] = bB_.y;             \
      acc[i_][6] = bB_.z; acc[i_][7] = bB_.w;                                 \
    }                                                                         \
  }

#define GEMM_STEP(ABUF, ASTR, WPTR)                                           \
  {                                                                           \
    const float4 w0_ = *(const float4*)((WPTR) + (size_t)k * 128 + cg * 8);   \
    const float4 w1_ = *(const float4*)((WPTR) + (size_t)k * 128 + cg * 8 + 4);\
    float wv_[8] = {w0_.x, w0_.y, w0_.z, w0_.w, w1_.x, w1_.y, w1_.z, w1_.w};  \
    float av_[4];                                                             \
    _Pragma("unroll") for (int i_ = 0; i_ < 4; ++i_)                          \
        av_[i_] = (ABUF)[(rg * 4 + i_) * (ASTR) + k];                         \
    _Pragma("unroll") for (int i_ = 0; i_ < 4; ++i_)                          \
      _Pragma("unroll") for (int j_ = 0; j_ < 8; ++j_)                        \
          acc[i_][j_] = fmaf(av_[i_], wv_[j_], acc[i_][j_]);                  \
  }

#define STORE_LDS_RELU(TBUF, TSTR)                                            \
  _Pragma("unroll") for (int i_ = 0; i_ < 4; ++i_) {                          \
    *(float4*)&(TBUF)[(rg * 4 + i_) * (TSTR) + cg * 8] =                      \
        make_float4(fmaxf(acc[i_][0], 0.f), fmaxf(acc[i_][1], 0.f),           \
                    fmaxf(acc[i_][2], 0.f), fmaxf(acc[i_][3], 0.f));          \
    *(float4*)&(TBUF)[(rg * 4 + i_) * (TSTR) + cg * 8 + 4] =                  \
        make_float4(fmaxf(acc[i_][4], 0.f), fmaxf(acc[i_][5], 0.f),           \
                    fmaxf(acc[i_][6], 0.f), fmaxf(acc[i_][7], 0.f));          \
  }

#define STORE_LDS(TBUF, TSTR)                                                 \
  _Pragma("unroll") for (int i_ = 0; i_ < 4; ++i_) {                          \
    *(float4*)&(TBUF)[(rg * 4 + i_) * (TSTR) + cg * 8] =                      \
        make_float4(acc[i_][0], acc[i_][1], acc[i_][2], acc[i_][3]);          \
    *(float4*)&(TBUF)[(rg * 4 + i_) * (TSTR) + cg * 8 + 4] =                  \
        make_float4(acc[i_][4], acc[i_][5], acc[i_][6], acc[i_][7]);          \
  }

// ---------------- GRU weight transpose: WT[k][j] = W[j][k] ----------------
__global__ void gru_transpose_kernel(const float* __restrict__ wih,
                                     const float* __restrict__ whh,
                                     float* __restrict__ wihT,
                                     float* __restrict__ whhT) {
  int idx = blockIdx.x * 256 + threadIdx.x;
  if (idx < 128 * 384) {
    int k = idx / 384;
    int j = idx - k * 384;
    wihT[idx] = wih[j * 128 + k];
    whhT[idx] = whh[j * 128 + k];
  }
}

// ---------------- encoder: h = relu(x@W1+b1)@W2+b2 ----------------
__global__ __launch_bounds__(256, 2)
void encoder_kernel(const float* __restrict__ x,
                    const float* __restrict__ w1, const float* __restrict__ b1,
                    const float* __restrict__ w2, const float* __restrict__ b2,
                    float* __restrict__ hout) {
  __shared__ float xa[64 * 132];
  __shared__ float tb[64 * 132];
  const int tid = threadIdx.x;
  const int cg = tid & 15, rg = tid >> 4;
  const int r0 = blockIdx.x * 64;
#pragma unroll
  for (int it = 0; it < 8; ++it) {
    int f = tid + it * 256;              // float4 index over [64][32]
    int row = f >> 5, c4 = f & 31;
    float4 v = make_float4(0.f, 0.f, 0.f, 0.f);
    int grow = r0 + row;
    if (grow < NN) v = *(const float4*)(x + (size_t)grow * 128 + c4 * 4);
    *(float4*)&xa[row * 132 + c4 * 4] = v;
  }
  __syncthreads();
  float acc[4][8];
  ACC_INIT(b1);
#pragma unroll 2
  for (int k = 0; k < 128; ++k) GEMM_STEP(xa, 132, w1);
  STORE_LDS_RELU(tb, 132);
  __syncthreads();
  ACC_INIT(b2);
#pragma unroll 2
  for (int k = 0; k < 128; ++k) GEMM_STEP(tb, 132, w2);
#pragma unroll
  for (int i = 0; i < 4; ++i) {
    int grow = r0 + rg * 4 + i;
    if (grow < NN) {
      *(float4*)(hout + (size_t)grow * 128 + cg * 8) =
          make_float4(acc[i][0], acc[i][1], acc[i][2], acc[i][3]);
      *(float4*)(hout + (size_t)grow * 128 + cg * 8 + 4) =
          make_float4(acc[i][4], acc[i][5], acc[i][6], acc[i][7]);
    }
  }
}

// ---------------- fused edge pipeline ----------------
// e_in = [h[dst] | h[src] | ea]  (64 edges x 288, LDS)
// e_emb = MLP2(e_in, et);  msg = MLP2(e_emb, msg);  atomicAdd(aggr[dst], msg)
__global__ __launch_bounds__(256, 1)
void edge_kernel(const float* __restrict__ h, const float* __restrict__ ea,
                 const int* __restrict__ esrc, const int* __restrict__ edst,
                 const float* __restrict__ w1, const float* __restrict__ b1,
                 const float* __restrict__ w2, const float* __restrict__ b2,
                 const float* __restrict__ w3, const float* __restrict__ b3,
                 const float* __restrict__ w4, const float* __restrict__ b4,
                 float* __restrict__ aggr) {
  __shared__ float ein[64 * 292];   // also reused (stride 132) for e_emb
  __shared__ float tb[64 * 132];
  __shared__ int eidx[128];         // [0:64) dst, [64:128) src
  const int tid = threadIdx.x, cg = tid & 15, rg = tid >> 4;
  const int e0 = blockIdx.x * 64;
  if (tid < 64) eidx[tid] = edst[e0 + tid];
  else if (tid < 128) eidx[tid] = esrc[e0 + tid - 64];
  __syncthreads();
#pragma unroll
  for (int it = 0; it < 18; ++it) {
    int f = tid + it * 256;           // float4 index over [64][72]
    int row = f / 72, c4 = f - row * 72;
    const float* sp;
    if (c4 < 32)       sp = h + (size_t)eidx[row] * 128 + c4 * 4;          // x_i = h[dst]
    else if (c4 < 64)  sp = h + (size_t)eidx[64 + row] * 128 + (c4 - 32) * 4; // x_j = h[src]
    else               sp = ea + (size_t)(e0 + row) * 32 + (c4 - 64) * 4;
    *(float4*)&ein[row * 292 + c4 * 4] = *(const float4*)sp;
  }
  __syncthreads();
  float acc[4][8];
  ACC_INIT(b1);                               // et hidden, K=288
#pragma unroll 2
  for (int k = 0; k < 288; ++k) GEMM_STEP(ein, 292, w1);
  STORE_LDS_RELU(tb, 132);
  __syncthreads();
  ACC_INIT(b2);                               // e_emb, K=128
#pragma unroll 2
  for (int k = 0; k < 128; ++k) GEMM_STEP(tb, 132, w2);
  STORE_LDS(ein, 132);                        // ein dead -> reuse as e_emb
  __syncthreads();
  ACC_INIT(b3);                               // msg hidden, K=128
#pragma unroll 2
  for (int k = 0; k < 128; ++k) GEMM_STEP(ein, 132, w3);
  STORE_LDS_RELU(tb, 132);
  __syncthreads();
  ACC_INIT(b4);                               // msg, K=128
#pragma unroll 2
  for (int k = 0; k < 128; ++k) GEMM_STEP(tb, 132, w4);
#pragma unroll
  for (int i = 0; i < 4; ++i) {
    float* ap = aggr + (size_t)eidx[rg * 4 + i] * 128 + cg * 8;
#pragma unroll
    for (int j = 0; j < 8; ++j) unsafeAtomicAdd(ap + j, acc[i][j]);
  }
}

// ---------------- update: h' = LN(h + MLP2([h|aggr])) ----------------
__global__ __launch_bounds__(256, 1)
void update_kernel(const float* __restrict__ h, const float* __restrict__ aggr,
                   const float* __restrict__ w1, const float* __restrict__ b1,
                   const float* __restrict__ w2, const float* __restrict__ b2,
                   const float* __restrict__ lng, const float* __restrict__ lnb,
                   float* __restrict__ hout) {
  __shared__ float ua[64 * 260];
  __shared__ float tb[64 * 132];
  const int tid = threadIdx.x, cg = tid & 15, rg = tid >> 4;
  const int r0 = blockIdx.x * 64;
#pragma unroll
  for (int it = 0; it < 16; ++it) {
    int f = tid + it * 256;           // float4 index over [64][64]
    int row = f >> 6, c4 = f & 63;
    int grow = r0 + row;
    float4 v = make_float4(0.f, 0.f, 0.f, 0.f);
    if (grow < NN)
      v = (c4 < 32) ? *(const float4*)(h + (size_t)grow * 128 + c4 * 4)
                    : *(const float4*)(aggr + (size_t)grow * 128 + (c4 - 32) * 4);
    *(float4*)&ua[row * 260 + c4 * 4] = v;
  }
  __syncthreads();
  float acc[4][8];
  ACC_INIT(b1);
#pragma unroll 2
  for (int k = 0; k < 256; ++k) GEMM_STEP(ua, 260, w1);
  STORE_LDS_RELU(tb, 132);
  __syncthreads();
  ACC_INIT(b2);
#pragma unroll 2
  for (int k = 0; k < 128; ++k) GEMM_STEP(tb, 132, w2);
  const float4 g0 = *(const float4*)(lng + cg * 8), g1 = *(const float4*)(lng + cg * 8 + 4);
  const float4 q0 = *(const float4*)(lnb + cg * 8), q1 = *(const float4*)(lnb + cg * 8 + 4);
  float gv[8] = {g0.x, g0.y, g0.z, g0.w, g1.x, g1.y, g1.z, g1.w};
  float bv[8] = {q0.x, q0.y, q0.z, q0.w, q1.x, q1.y, q1.z, q1.w};
#pragma unroll
  for (int i = 0; i < 4; ++i) {
    int lr = rg * 4 + i;
    float y[8];
    float s = 0.f, ss = 0.f;
#pragma unroll
    for (int j = 0; j < 8; ++j) {
      y[j] = acc[i][j] + ua[lr * 260 + cg * 8 + j];  // residual (h is cols 0..127)
      s += y[j]; ss += y[j] * y[j];
    }
#pragma unroll
    for (int m = 1; m < 16; m <<= 1) {
      s += __shfl_xor(s, m, 16);
      ss += __shfl_xor(ss, m, 16);
    }
    float mean = s * (1.f / 128.f);
    float var = ss * (1.f / 128.f) - mean * mean;
    float rstd = rsqrtf(var + 1e-5f);
    int grow = r0 + lr;
    if (grow < NN) {
      float o[8];
#pragma unroll
      for (int j = 0; j < 8; ++j) o[j] = (y[j] - mean) * rstd * gv[j] + bv[j];
      *(float4*)(hout + (size_t)grow * 128 + cg * 8) = make_float4(o[0], o[1], o[2], o[3]);
      *(float4*)(hout + (size_t)grow * 128 + cg * 8 + 4) = make_float4(o[4], o[5], o[6], o[7]);
    }
  }
}

// ---------------- GRU cell (torch semantics) ----------------
__global__ __launch_bounds__(256, 4)
void gru_kernel(const float* __restrict__ h, const float* __restrict__ hprev,
                const float* __restrict__ wihT, const float* __restrict__ whhT,
                const float* __restrict__ bih, const float* __restrict__ bhh,
                float* __restrict__ out) {
  __shared__ float ha[32 * 132];
  __shared__ float hp[32 * 132];
  const int tid = threadIdx.x, cg = tid & 15, rg = tid >> 4;
  const int r0 = blockIdx.x * 32;
#pragma unroll
  for (int it = 0; it < 4; ++it) {
    int f = tid + it * 256;
    int row = f >> 5, c4 = f & 31;
    int grow = r0 + row;
    float4 va = make_float4(0.f, 0.f, 0.f, 0.f), vp = va;
    if (grow < NN) {
      va = *(const float4*)(h + (size_t)grow * 128 + c4 * 4);
      vp = *(const float4*)(hprev + (size_t)grow * 128 + c4 * 4);
    }
    *(float4*)&ha[row * 132 + c4 * 4] = va;
    *(float4*)&hp[row * 132 + c4 * 4] = vp;
  }
  __syncthreads();
  float rgate[2][8], zgate[2][8];
#pragma unroll
  for (int c = 0; c < 2; ++c) {
    float acc[2][8];
#pragma unroll
    for (int j = 0; j < 8; ++j) {
      float bsum = bih[c * 128 + cg * 8 + j] + bhh[c * 128 + cg * 8 + j];
      acc[0][j] = bsum; acc[1][j] = bsum;
    }
    for (int k = 0; k < 128; ++k) {
      const float* wi = wihT + (size_t)k * 384 + c * 128 + cg * 8;
      const float* wh = whhT + (size_t)k * 384 + c * 128 + cg * 8;
      const float4 wi0 = *(const float4*)wi, wi1 = *(const float4*)(wi + 4);
      const float4 wh0 = *(const float4*)wh, wh1 = *(const float4*)(wh + 4);
      float wiv[8] = {wi0.x, wi0.y, wi0.z, wi0.w, wi1.x, wi1.y, wi1.z, wi1.w};
      float whv[8] = {wh0.x, wh0.y, wh0.z, wh0.w, wh1.x, wh1.y, wh1.z, wh1.w};
      float a0 = ha[(rg * 2 + 0) * 132 + k], a1 = ha[(rg * 2 + 1) * 132 + k];
      float p0 = hp[(rg * 2 + 0) * 132 + k], p1 = hp[(rg * 2 + 1) * 132 + k];
#pragma unroll
      for (int j = 0; j < 8; ++j) {
        acc[0][j] = fmaf(a0, wiv[j], acc[0][j]);
        acc[1][j] = fmaf(a1, wiv[j], acc[1][j]);
        acc[0][j] = fmaf(p0, whv[j], acc[0][j]);
        acc[1][j] = fmaf(p1, whv[j], acc[1][j]);
      }
    }
#pragma unroll
    for (int i = 0; i < 2; ++i)
#pragma unroll
      for (int j = 0; j < 8; ++j) {
        float sg = 1.f / (1.f + __expf(-acc[i][j]));
        if (c == 0) rgate[i][j] = sg; else zgate[i][j] = sg;
      }
  }
  float ai[2][8], ah[2][8];
#pragma unroll
  for (int j = 0; j < 8; ++j) {
    float bi = bih[256 + cg * 8 + j], bh = bhh[256 + cg * 8 + j];
    ai[0][j] = bi; ai[1][j] = bi;
    ah[0][j] = bh; ah[1][j] = bh;
  }
  for (int k = 0; k < 128; ++k) {
    const float* wi = wihT + (size_t)k * 384 + 256 + cg * 8;
    const float* wh = whhT + (size_t)k * 384 + 256 + cg * 8;
    const float4 wi0 = *(const float4*)wi, wi1 = *(const float4*)(wi + 4);
    const float4 wh0 = *(const float4*)wh, wh1 = *(const float4*)(wh + 4);
    float wiv[8] = {wi0.x, wi0.y, wi0.z, wi0.w, wi1.x, wi1.y, wi1.z, wi1.w};
    float whv[8] = {wh0.x, wh0.y, wh0.z, wh0.w, wh1.x, wh1.y, wh1.z, wh1.w};
    float a0 = ha[(rg * 2 + 0) * 132 + k], a1 = ha[(rg * 2 + 1) * 132 + k];
    float p0 = hp[(rg * 2 + 0) * 132 + k], p1 = hp[(rg * 2 + 1) * 132 + k];
#pragma unroll
    for (int j = 0; j < 8; ++j) {
      ai[0][j] = fmaf(a0, wiv[j], ai[0][j]);
      ai[1][j] = fmaf(a1, wiv[j], ai[1][j]);
      ah[0][j] = fmaf(p0, whv[j], ah[0][j]);
      ah[1][j] = fmaf(p1, whv[j], ah[1][j]);
    }
  }
#pragma unroll
  for (int i = 0; i < 2; ++i) {
    int grow = r0 + rg * 2 + i;
    if (grow >= NN) continue;
    float o[8];
#pragma unroll
    for (int j = 0; j < 8; ++j) {
      float nn_ = tanhf(fmaf(rgate[i][j], ah[i][j], ai[i][j]));
      float hpv = hp[(rg * 2 + i) * 132 + cg * 8 + j];
      o[j] = (1.f - zgate[i][j]) * nn_ + zgate[i][j] * hpv;
    }
    *(float4*)(out + (size_t)grow * 128 + cg * 8) = make_float4(o[0], o[1], o[2], o[3]);
    *(float4*)(out + (size_t)grow * 128 + cg * 8 + 4) = make_float4(o[4], o[5], o[6], o[7]);
  }
}

// ---------------- launch ----------------
extern "C" void kernel_launch(void* const* d_in, const int* in_sizes, int n_in,
                              void* d_out, int out_size, void* d_ws, size_t ws_size,
                              hipStream_t stream) {
  (void)in_sizes; (void)n_in; (void)out_size; (void)ws_size;
  const float* x         = (const float*)d_in[0];
  const float* edge_attr = (const float*)d_in[1];
  const float* h_prev    = (const float*)d_in[2];
  const float* enc_w1    = (const float*)d_in[3];
  const float* enc_b1    = (const float*)d_in[4];
  const float* enc_w2    = (const float*)d_in[5];
  const float* enc_b2    = (const float*)d_in[6];
  const float* et_w1     = (const float*)d_in[7];
  const float* et_b1     = (const float*)d_in[8];
  const float* et_w2     = (const float*)d_in[9];
  const float* et_b2     = (const float*)d_in[10];
  const float* msg_w1    = (const float*)d_in[11];
  const float* msg_b1    = (const float*)d_in[12];
  const float* msg_w2    = (const float*)d_in[13];
  const float* msg_b2    = (const float*)d_in[14];
  const float* upd_w1    = (const float*)d_in[15];
  const float* upd_b1    = (const float*)d_in[16];
  const float* upd_w2    = (const float*)d_in[17];
  const float* upd_b2    = (const float*)d_in[18];
  const float* ln_g      = (const float*)d_in[19];
  const float* ln_b      = (const float*)d_in[20];
  const float* gru_wih   = (const float*)d_in[21];
  const float* gru_whh   = (const float*)d_in[22];
  const float* gru_bih   = (const float*)d_in[23];
  const float* gru_bhh   = (const float*)d_in[24];
  const int* edge_index  = (const int*)d_in[25];
  const int* esrc = edge_index;        // edge_index[0]
  const int* edst = edge_index + NE;   // edge_index[1]

  float* ws   = (float*)d_ws;
  float* h_a  = ws;                                  // N*128
  float* aggr = ws + (size_t)NN * 128;               // N*128
  float* wihT = ws + (size_t)2 * NN * 128;           // 128*384
  float* whhT = wihT + 128 * 384;                    // 128*384
  float* h_b  = (float*)d_out;                       // reuse output buffer as ping-pong

  gru_transpose_kernel<<<192, 256, 0, stream>>>(gru_wih, gru_whh, wihT, whhT);
  encoder_kernel<<<(NN + 63) / 64, 256, 0, stream>>>(x, enc_w1, enc_b1, enc_w2, enc_b2, h_a);

  float* hc = h_a;
  float* hn = h_b;
  for (int l = 0; l < 4; ++l) {
    hipMemsetAsync(aggr, 0, (size_t)NN * 128 * sizeof(float), stream);
    edge_kernel<<<NE / 64, 256, 0, stream>>>(
        hc, edge_attr, esrc, edst,
        et_w1 + (size_t)l * 288 * 128, et_b1 + l * 128,
        et_w2 + (size_t)l * 128 * 128, et_b2 + l * 128,
        msg_w1 + (size_t)l * 128 * 128, msg_b1 + l * 128,
        msg_w2 + (size_t)l * 128 * 128, msg_b2 + l * 128,
        aggr);
    update_kernel<<<(NN + 63) / 64, 256, 0, stream>>>(
        hc, aggr,
        upd_w1 + (size_t)l * 256 * 128, upd_b1 + l * 128,
        upd_w2 + (size_t)l * 128 * 128, upd_b2 + l * 128,
        ln_g, ln_b, hn);
    float* t = hc; hc = hn; hn = t;
  }
  // after 4 swaps: hc == h_a
  gru_kernel<<<(NN + 31) / 32, 256, 0, stream>>>(hc, h_prev, wihT, whhT,
                                                 gru_bih, gru_bhh, (float*)d_out);
}

// Round 2
// 3474.347 us; speedup vs baseline: 6.2595x; 6.2595x over previous
//
#include <hip/hip_runtime.h>
#include <hip/hip_bf16.h>
#include <cstdint>

#define NN 50000
#define NE 800000

typedef _Float16 f16;
typedef f16 f16x8 __attribute__((ext_vector_type(8)));
typedef f16 f16x4 __attribute__((ext_vector_type(4)));
typedef float f32x4 __attribute__((ext_vector_type(4)));

#define EIN_STR 296   // f16 stride for e_in tile (592B, 16B aligned, odd dword-ish)
#define T_STR   136   // f16 stride for 128-col intermediates (272B, 16B aligned)

// ============================================================================
// Weight pre-pack: f16 MFMA B-fragment layout.
// Per layer: units = G1(K=288): 72, G2: 32, G3: 32, G4: 32  -> 168 units.
// unit = kc*8 + ct (per GEMM); element: [lane][i] -> w[kc*32+(lane>>4)*8+i][ct*16+(lane&15)]
// ============================================================================
__global__ void pack_w_kernel(const float* __restrict__ et_w1,
                              const float* __restrict__ et_w2,
                              const float* __restrict__ msg_w1,
                              const float* __restrict__ msg_w2,
                              f16* __restrict__ wpack) {
  int idx = blockIdx.x * 256 + threadIdx.x;
  if (idx >= 4 * 86016) return;
  int l = idx / 86016;
  int rem = idx - l * 86016;
  int unit = rem >> 9;         // /512
  int e = rem & 511;
  int ln = e >> 3, i = e & 7;
  const float* src;
  int ul;
  if (unit < 72)       { src = et_w1  + (size_t)l * 288 * 128; ul = unit; }
  else if (unit < 104) { src = et_w2  + (size_t)l * 128 * 128; ul = unit - 72; }
  else if (unit < 136) { src = msg_w1 + (size_t)l * 128 * 128; ul = unit - 104; }
  else                 { src = msg_w2 + (size_t)l * 128 * 128; ul = unit - 136; }
  int kc = ul >> 3, ct = ul & 7;
  int k = kc * 32 + (ln >> 4) * 8 + i;
  int col = ct * 16 + (ln & 15);
  wpack[idx] = (f16)src[k * 128 + col];
}

// ============================================================================
// Fused edge pipeline, f16 MFMA.
// Block = 64 edges, 256 threads = 4 waves, wave (wr,wc) owns 32 rows x 64 cols.
// ============================================================================
#define MFMA_GEMM(ABASE, ASTR, UNIT0, NKC, BIAS, ACC)                          \
  {                                                                            \
    _Pragma("unroll") for (int ct = 0; ct < 4; ++ct) {                         \
      float bv_ = (BIAS)[wc * 64 + ct * 16 + cl];                              \
      ACC[0][ct] = (f32x4){bv_, bv_, bv_, bv_};                                \
      ACC[1][ct] = ACC[0][ct];                                                 \
    }                                                                          \
    _Pragma("unroll 2") for (int kc = 0; kc < (NKC); ++kc) {                   \
      f16x8 a0_ = *(const f16x8*)&(ABASE)[(wr * 32 + cl) * (ASTR) + kc * 32 + kh * 8]; \
      f16x8 a1_ = *(const f16x8*)&(ABASE)[(wr * 32 + 16 + cl) * (ASTR) + kc * 32 + kh * 8]; \
      _Pragma("unroll") for (int ct = 0; ct < 4; ++ct) {                       \
        f16x8 b_ = *(const f16x8*)&wp[(size_t)(((UNIT0) + kc * 8 + wc * 4 + ct) * 64 + lane) * 8]; \
        ACC[0][ct] = __builtin_amdgcn_mfma_f32_16x16x32_f16(a0_, b_, ACC[0][ct], 0, 0, 0); \
        ACC[1][ct] = __builtin_amdgcn_mfma_f32_16x16x32_f16(a1_, b_, ACC[1][ct], 0, 0, 0); \
      }                                                                        \
    }                                                                          \
  }

#define STORE_C(DST, DSTR, DORELU, ACC)                                        \
  _Pragma("unroll") for (int rt = 0; rt < 2; ++rt)                             \
    _Pragma("unroll") for (int ct = 0; ct < 4; ++ct)                           \
      _Pragma("unroll") for (int i = 0; i < 4; ++i) {                          \
        float v_ = ACC[rt][ct][i];                                             \
        if (DORELU) v_ = fmaxf(v_, 0.f);                                       \
        (DST)[(wr * 32 + rt * 16 + kh * 4 + i) * (DSTR) + wc * 64 + ct * 16 + cl] = (f16)v_; \
      }

__global__ __launch_bounds__(256, 2)
void edge_mfma_kernel(const float* __restrict__ h, const float* __restrict__ ea,
                      const int* __restrict__ esrc, const int* __restrict__ edst,
                      const f16* __restrict__ wp,
                      const float* __restrict__ b1, const float* __restrict__ b2,
                      const float* __restrict__ b3, const float* __restrict__ b4,
                      float* __restrict__ aggr) {
  __shared__ f16 ein[64 * EIN_STR];   // e_in [64][288]; later reused (stride T_STR) for e_emb
  __shared__ f16 tb[64 * T_STR];
  __shared__ int eidx[128];
  const int tid = threadIdx.x;
  const int lane = tid & 63;
  const int wv = tid >> 6;
  const int wr = wv >> 1, wc = wv & 1;
  const int cl = lane & 15;
  const int kh = lane >> 4;
  const int e0 = blockIdx.x * 64;
  if (tid < 64) eidx[tid] = edst[e0 + tid];
  else if (tid < 128) eidx[tid] = esrc[e0 + tid - 64];
  __syncthreads();
  // stage e_in = [h[dst] | h[src] | ea] -> f16 LDS
#pragma unroll
  for (int it = 0; it < 18; ++it) {
    int f = tid + it * 256;              // float4-group index over [64][72]
    int row = f / 72, c4 = f - row * 72;
    const float* sp;
    if (c4 < 32)      sp = h + (size_t)eidx[row] * 128 + c4 * 4;           // x_i = h[dst]
    else if (c4 < 64) sp = h + (size_t)eidx[64 + row] * 128 + (c4 - 32) * 4; // x_j = h[src]
    else              sp = ea + (size_t)(e0 + row) * 32 + (c4 - 64) * 4;
    float4 v = *(const float4*)sp;
    *(f16x4*)&ein[row * EIN_STR + c4 * 4] =
        (f16x4){(f16)v.x, (f16)v.y, (f16)v.z, (f16)v.w};
  }
  __syncthreads();
  f32x4 acc[2][4];
  f16* emb = ein;                        // reuse e_in space for e_emb (stride T_STR)
  MFMA_GEMM(ein, EIN_STR, 0, 9, b1, acc);      // et hidden, K=288
  STORE_C(tb, T_STR, 1, acc);
  __syncthreads();
  MFMA_GEMM(tb, T_STR, 72, 4, b2, acc);        // e_emb, K=128
  STORE_C(emb, T_STR, 0, acc);
  __syncthreads();
  MFMA_GEMM(emb, T_STR, 104, 4, b3, acc);      // msg hidden, K=128
  STORE_C(tb, T_STR, 1, acc);
  __syncthreads();
  MFMA_GEMM(tb, T_STR, 136, 4, b4, acc);       // msg, K=128
#pragma unroll
  for (int rt = 0; rt < 2; ++rt) {
#pragma unroll
    for (int i = 0; i < 4; ++i) {
      int row = wr * 32 + rt * 16 + kh * 4 + i;
      float* ap = aggr + (size_t)eidx[row] * 128 + wc * 64 + cl;
#pragma unroll
      for (int ct = 0; ct < 4; ++ct)
        unsafeAtomicAdd(ap + ct * 16, acc[rt][ct][i]);
    }
  }
}

// ============================================================================
// fp32 register-tiled GEMM machinery for node-side kernels (unchanged from R1)
// ============================================================================
#define ACC_INIT(BPTR)                                                        \
  {                                                                           \
    const float4 bA_ = *(const float4*)((BPTR) + cg * 8);                     \
    const float4 bB_ = *(const float4*)((BPTR) + cg * 8 + 4);                 \
    _Pragma("unroll") for (int i_ = 0; i_ < 4; ++i_) {                        \
      acc[i_][0] = bA_.x; acc[i_][1] = bA_.y; acc[i_][2] = bA_.z;             \
      acc[i_][3] = bA_.w; acc[i_][4] = bB_.x; acc[i_][5] = bB_.y;             \
      acc[i_][6] = bB_.z; acc[i_][7] = bB_.w;                                 \
    }                                                                         \
  }

#define GEMM_STEP(ABUF, ASTR, WPTR)                                           \
  {                                                                           \
    const float4 w0_ = *(const float4*)((WPTR) + (size_t)k * 128 + cg * 8);   \
    const float4 w1_ = *(const float4*)((WPTR) + (size_t)k * 128 + cg * 8 + 4);\
    float wv_[8] = {w0_.x, w0_.y, w0_.z, w0_.w, w1_.x, w1_.y, w1_.z, w1_.w};  \
    float av_[4];                                                             \
    _Pragma("unroll") for (int i_ = 0; i_ < 4; ++i_)                          \
        av_[i_] = (ABUF)[(rg * 4 + i_) * (ASTR) + k];                         \
    _Pragma("unroll") for (int i_ = 0; i_ < 4; ++i_)                          \
      _Pragma("unroll") for (int j_ = 0; j_ < 8; ++j_)                        \
          acc[i_][j_] = fmaf(av_[i_], wv_[j_], acc[i_][j_]);                  \
  }

#define STORE_LDS_RELU(TBUF, TSTR)                                            \
  _Pragma("unroll") for (int i_ = 0; i_ < 4; ++i_) {                          \
    *(float4*)&(TBUF)[(rg * 4 + i_) * (TSTR) + cg * 8] =                      \
        make_float4(fmaxf(acc[i_][0], 0.f), fmaxf(acc[i_][1], 0.f),           \
                    fmaxf(acc[i_][2], 0.f), fmaxf(acc[i_][3], 0.f));          \
    *(float4*)&(TBUF)[(rg * 4 + i_) * (TSTR) + cg * 8 + 4] =                  \
        make_float4(fmaxf(acc[i_][4], 0.f), fmaxf(acc[i_][5], 0.f),           \
                    fmaxf(acc[i_][6], 0.f), fmaxf(acc[i_][7], 0.f));          \
  }

__global__ void gru_transpose_kernel(const float* __restrict__ wih,
                                     const float* __restrict__ whh,
                                     float* __restrict__ wihT,
                                     float* __restrict__ whhT) {
  int idx = blockIdx.x * 256 + threadIdx.x;
  if (idx < 128 * 384) {
    int k = idx / 384;
    int j = idx - k * 384;
    wihT[idx] = wih[j * 128 + k];
    whhT[idx] = whh[j * 128 + k];
  }
}

__global__ __launch_bounds__(256, 2)
void encoder_kernel(const float* __restrict__ x,
                    const float* __restrict__ w1, const float* __restrict__ b1,
                    const float* __restrict__ w2, const float* __restrict__ b2,
                    float* __restrict__ hout) {
  __shared__ float xa[64 * 132];
  __shared__ float tb[64 * 132];
  const int tid = threadIdx.x;
  const int cg = tid & 15, rg = tid >> 4;
  const int r0 = blockIdx.x * 64;
#pragma unroll
  for (int it = 0; it < 8; ++it) {
    int f = tid + it * 256;
    int row = f >> 5, c4 = f & 31;
    float4 v = make_float4(0.f, 0.f, 0.f, 0.f);
    int grow = r0 + row;
    if (grow < NN) v = *(const float4*)(x + (size_t)grow * 128 + c4 * 4);
    *(float4*)&xa[row * 132 + c4 * 4] = v;
  }
  __syncthreads();
  float acc[4][8];
  ACC_INIT(b1);
#pragma unroll 2
  for (int k = 0; k < 128; ++k) GEMM_STEP(xa, 132, w1);
  STORE_LDS_RELU(tb, 132);
  __syncthreads();
  ACC_INIT(b2);
#pragma unroll 2
  for (int k = 0; k < 128; ++k) GEMM_STEP(tb, 132, w2);
#pragma unroll
  for (int i = 0; i < 4; ++i) {
    int grow = r0 + rg * 4 + i;
    if (grow < NN) {
      *(float4*)(hout + (size_t)grow * 128 + cg * 8) =
          make_float4(acc[i][0], acc[i][1], acc[i][2], acc[i][3]);
      *(float4*)(hout + (size_t)grow * 128 + cg * 8 + 4) =
          make_float4(acc[i][4], acc[i][5], acc[i][6], acc[i][7]);
    }
  }
}

__global__ __launch_bounds__(256, 1)
void update_kernel(const float* __restrict__ h, const float* __restrict__ aggr,
                   const float* __restrict__ w1, const float* __restrict__ b1,
                   const float* __restrict__ w2, const float* __restrict__ b2,
                   const float* __restrict__ lng, const float* __restrict__ lnb,
                   float* __restrict__ hout) {
  __shared__ float ua[64 * 260];
  __shared__ float tb[64 * 132];
  const int tid = threadIdx.x, cg = tid & 15, rg = tid >> 4;
  const int r0 = blockIdx.x * 64;
#pragma unroll
  for (int it = 0; it < 16; ++it) {
    int f = tid + it * 256;
    int row = f >> 6, c4 = f & 63;
    int grow = r0 + row;
    float4 v = make_float4(0.f, 0.f, 0.f, 0.f);
    if (grow < NN)
      v = (c4 < 32) ? *(const float4*)(h + (size_t)grow * 128 + c4 * 4)
                    : *(const float4*)(aggr + (size_t)grow * 128 + (c4 - 32) * 4);
    *(float4*)&ua[row * 260 + c4 * 4] = v;
  }
  __syncthreads();
  float acc[4][8];
  ACC_INIT(b1);
#pragma unroll 2
  for (int k = 0; k < 256; ++k) GEMM_STEP(ua, 260, w1);
  STORE_LDS_RELU(tb, 132);
  __syncthreads();
  ACC_INIT(b2);
#pragma unroll 2
  for (int k = 0; k < 128; ++k) GEMM_STEP(tb, 132, w2);
  const float4 g0 = *(const float4*)(lng + cg * 8), g1 = *(const float4*)(lng + cg * 8 + 4);
  const float4 q0 = *(const float4*)(lnb + cg * 8), q1 = *(const float4*)(lnb + cg * 8 + 4);
  float gv[8] = {g0.x, g0.y, g0.z, g0.w, g1.x, g1.y, g1.z, g1.w};
  float bv[8] = {q0.x, q0.y, q0.z, q0.w, q1.x, q1.y, q1.z, q1.w};
#pragma unroll
  for (int i = 0; i < 4; ++i) {
    int lr = rg * 4 + i;
    float y[8];
    float s = 0.f, ss = 0.f;
#pragma unroll
    for (int j = 0; j < 8; ++j) {
      y[j] = acc[i][j] + ua[lr * 260 + cg * 8 + j];
      s += y[j]; ss += y[j] * y[j];
    }
#pragma unroll
    for (int m = 1; m < 16; m <<= 1) {
      s += __shfl_xor(s, m, 16);
      ss += __shfl_xor(ss, m, 16);
    }
    float mean = s * (1.f / 128.f);
    float var = ss * (1.f / 128.f) - mean * mean;
    float rstd = rsqrtf(var + 1e-5f);
    int grow = r0 + lr;
    if (grow < NN) {
      float o[8];
#pragma unroll
      for (int j = 0; j < 8; ++j) o[j] = (y[j] - mean) * rstd * gv[j] + bv[j];
      *(float4*)(hout + (size_t)grow * 128 + cg * 8) = make_float4(o[0], o[1], o[2], o[3]);
      *(float4*)(hout + (size_t)grow * 128 + cg * 8 + 4) = make_float4(o[4], o[5], o[6], o[7]);
    }
  }
}

__global__ __launch_bounds__(256, 4)
void gru_kernel(const float* __restrict__ h, const float* __restrict__ hprev,
                const float* __restrict__ wihT, const float* __restrict__ whhT,
                const float* __restrict__ bih, const float* __restrict__ bhh,
                float* __restrict__ out) {
  __shared__ float ha[32 * 132];
  __shared__ float hp[32 * 132];
  const int tid = threadIdx.x, cg = tid & 15, rg = tid >> 4;
  const int r0 = blockIdx.x * 32;
#pragma unroll
  for (int it = 0; it < 4; ++it) {
    int f = tid + it * 256;
    int row = f >> 5, c4 = f & 31;
    int grow = r0 + row;
    float4 va = make_float4(0.f, 0.f, 0.f, 0.f), vp = va;
    if (grow < NN) {
      va = *(const float4*)(h + (size_t)grow * 128 + c4 * 4);
      vp = *(const float4*)(hprev + (size_t)grow * 128 + c4 * 4);
    }
    *(float4*)&ha[row * 132 + c4 * 4] = va;
    *(float4*)&hp[row * 132 + c4 * 4] = vp;
  }
  __syncthreads();
  float rgate[2][8], zgate[2][8];
#pragma unroll
  for (int c = 0; c < 2; ++c) {
    float acc[2][8];
#pragma unroll
    for (int j = 0; j < 8; ++j) {
      float bsum = bih[c * 128 + cg * 8 + j] + bhh[c * 128 + cg * 8 + j];
      acc[0][j] = bsum; acc[1][j] = bsum;
    }
    for (int k = 0; k < 128; ++k) {
      const float* wi = wihT + (size_t)k * 384 + c * 128 + cg * 8;
      const float* wh = whhT + (size_t)k * 384 + c * 128 + cg * 8;
      const float4 wi0 = *(const float4*)wi, wi1 = *(const float4*)(wi + 4);
      const float4 wh0 = *(const float4*)wh, wh1 = *(const float4*)(wh + 4);
      float wiv[8] = {wi0.x, wi0.y, wi0.z, wi0.w, wi1.x, wi1.y, wi1.z, wi1.w};
      float whv[8] = {wh0.x, wh0.y, wh0.z, wh0.w, wh1.x, wh1.y, wh1.z, wh1.w};
      float a0 = ha[(rg * 2 + 0) * 132 + k], a1 = ha[(rg * 2 + 1) * 132 + k];
      float p0 = hp[(rg * 2 + 0) * 132 + k], p1 = hp[(rg * 2 + 1) * 132 + k];
#pragma unroll
      for (int j = 0; j < 8; ++j) {
        acc[0][j] = fmaf(a0, wiv[j], acc[0][j]);
        acc[1][j] = fmaf(a1, wiv[j], acc[1][j]);
        acc[0][j] = fmaf(p0, whv[j], acc[0][j]);
        acc[1][j] = fmaf(p1, whv[j], acc[1][j]);
      }
    }
#pragma unroll
    for (int i = 0; i < 2; ++i)
#pragma unroll
      for (int j = 0; j < 8; ++j) {
        float sg = 1.f / (1.f + __expf(-acc[i][j]));
        if (c == 0) rgate[i][j] = sg; else zgate[i][j] = sg;
      }
  }
  float ai[2][8], ah[2][8];
#pragma unroll
  for (int j = 0; j < 8; ++j) {
    float bi = bih[256 + cg * 8 + j], bh = bhh[256 + cg * 8 + j];
    ai[0][j] = bi; ai[1][j] = bi;
    ah[0][j] = bh; ah[1][j] = bh;
  }
  for (int k = 0; k < 128; ++k) {
    const float* wi = wihT + (size_t)k * 384 + 256 + cg * 8;
    const float* wh = whhT + (size_t)k * 384 + 256 + cg * 8;
    const float4 wi0 = *(const float4*)wi, wi1 = *(const float4*)(wi + 4);
    const float4 wh0 = *(const float4*)wh, wh1 = *(const float4*)(wh + 4);
    float wiv[8] = {wi0.x, wi0.y, wi0.z, wi0.w, wi1.x, wi1.y, wi1.z, wi1.w};
    float whv[8] = {wh0.x, wh0.y, wh0.z, wh0.w, wh1.x, wh1.y, wh1.z, wh1.w};
    float a0 = ha[(rg * 2 + 0) * 132 + k], a1 = ha[(rg * 2 + 1) * 132 + k];
    float p0 = hp[(rg * 2 + 0) * 132 + k], p1 = hp[(rg * 2 + 1) * 132 + k];
#pragma unroll
    for (int j = 0; j < 8; ++j) {
      ai[0][j] = fmaf(a0, wiv[j], ai[0][j]);
      ai[1][j] = fmaf(a1, wiv[j], ai[1][j]);
      ah[0][j] = fmaf(p0, whv[j], ah[0][j]);
      ah[1][j] = fmaf(p1, whv[j], ah[1][j]);
    }
  }
#pragma unroll
  for (int i = 0; i < 2; ++i) {
    int grow = r0 + rg * 2 + i;
    if (grow >= NN) continue;
    float o[8];
#pragma unroll
    for (int j = 0; j < 8; ++j) {
      float nn_ = tanhf(fmaf(rgate[i][j], ah[i][j], ai[i][j]));
      float hpv = hp[(rg * 2 + i) * 132 + cg * 8 + j];
      o[j] = (1.f - zgate[i][j]) * nn_ + zgate[i][j] * hpv;
    }
    *(float4*)(out + (size_t)grow * 128 + cg * 8) = make_float4(o[0], o[1], o[2], o[3]);
    *(float4*)(out + (size_t)grow * 128 + cg * 8 + 4) = make_float4(o[4], o[5], o[6], o[7]);
  }
}

// ---------------- launch ----------------
extern "C" void kernel_launch(void* const* d_in, const int* in_sizes, int n_in,
                              void* d_out, int out_size, void* d_ws, size_t ws_size,
                              hipStream_t stream) {
  (void)in_sizes; (void)n_in; (void)out_size; (void)ws_size;
  const float* x         = (const float*)d_in[0];
  const float* edge_attr = (const float*)d_in[1];
  const float* h_prev    = (const float*)d_in[2];
  const float* enc_w1    = (const float*)d_in[3];
  const float* enc_b1    = (const float*)d_in[4];
  const float* enc_w2    = (const float*)d_in[5];
  const float* enc_b2    = (const float*)d_in[6];
  const float* et_w1     = (const float*)d_in[7];
  const float* et_b1     = (const float*)d_in[8];
  const float* et_w2     = (const float*)d_in[9];
  const float* et_b2     = (const float*)d_in[10];
  const float* msg_w1    = (const float*)d_in[11];
  const float* msg_b1    = (const float*)d_in[12];
  const float* msg_w2    = (const float*)d_in[13];
  const float* msg_b2    = (const float*)d_in[14];
  const float* upd_w1    = (const float*)d_in[15];
  const float* upd_b1    = (const float*)d_in[16];
  const float* upd_w2    = (const float*)d_in[17];
  const float* upd_b2    = (const float*)d_in[18];
  const float* ln_g      = (const float*)d_in[19];
  const float* ln_b      = (const float*)d_in[20];
  const float* gru_wih   = (const float*)d_in[21];
  const float* gru_whh   = (const float*)d_in[22];
  const float* gru_bih   = (const float*)d_in[23];
  const float* gru_bhh   = (const float*)d_in[24];
  const int* edge_index  = (const int*)d_in[25];
  const int* esrc = edge_index;        // edge_index[0]
  const int* edst = edge_index + NE;   // edge_index[1]

  float* ws   = (float*)d_ws;
  float* h_a  = ws;                                  // N*128
  float* aggr = ws + (size_t)NN * 128;               // N*128
  float* wihT = ws + (size_t)2 * NN * 128;           // 128*384
  float* whhT = wihT + 128 * 384;                    // 128*384
  f16*   wpack = (f16*)(whhT + 128 * 384);           // 4*86016 f16
  float* h_b  = (float*)d_out;                       // ping-pong via output buffer

  gru_transpose_kernel<<<192, 256, 0, stream>>>(gru_wih, gru_whh, wihT, whhT);
  pack_w_kernel<<<(4 * 86016 + 255) / 256, 256, 0, stream>>>(et_w1, et_w2, msg_w1, msg_w2, wpack);
  encoder_kernel<<<(NN + 63) / 64, 256, 0, stream>>>(x, enc_w1, enc_b1, enc_w2, enc_b2, h_a);

  float* hc = h_a;
  float* hn = h_b;
  for (int l = 0; l < 4; ++l) {
    hipMemsetAsync(aggr, 0, (size_t)NN * 128 * sizeof(float), stream);
    edge_mfma_kernel<<<NE / 64, 256, 0, stream>>>(
        hc, edge_attr, esrc, edst,
        wpack + (size_t)l * 86016,
        et_b1 + l * 128, et_b2 + l * 128,
        msg_b1 + l * 128, msg_b2 + l * 128,
        aggr);
    update_kernel<<<(NN + 63) / 64, 256, 0, stream>>>(
        hc, aggr,
        upd_w1 + (size_t)l * 256 * 128, upd_b1 + l * 128,
        upd_w2 + (size_t)l * 128 * 128, upd_b2 + l * 128,
        ln_g, ln_b, hn);
    float* t = hc; hc = hn; hn = t;
  }
  // after 4 swaps: hc == h_a
  gru_kernel<<<(NN + 31) / 32, 256, 0, stream>>>(hc, h_prev, wihT, whhT,
                                                 gru_bih, gru_bhh, (float*)d_out);
}